// Round 1
// baseline (2490.196 us; speedup 1.0000x reference)
//
#include <hip/hip_runtime.h>

// ---------------------------------------------------------------------------
// BidirectionalMLP equilibrium relaxation on MI355X.
// s1,s2: [256,4096], s3: [256,10].  25 steps of:
//   s1' = clip(0.5*s1 + CC + 0.25*(r2@bw1))          CC = 0.25*(rx@fw0), const
//   s2' = clip(0.5*s2 + 0.25*(r1@fw1) + 0.25*(r3@bw2))
//   s3' = clip((0.5-beta)*s3 + 0.5*(r2@fw2) + beta*y)
// bf16 MFMA 16x16x32, fp32 accum. Weights transposed once to [N][K] bf16.
// Round 4: latency-bound fix (MfmaUtil 7.8%, VALUBusy 9.7%, all pipes idle,
// ~3070 cy/K-step vs ~135 cy of work). Two changes:
//   (1) 2-phase double-buffered pipeline: issue next tile's global_load_lds
//       BEFORE computing the current tile; single __syncthreads per K-step.
//       The barrier's vmcnt(0) drain now only pays residual latency.
//   (2) BM 64->128 (tile 128x64): 2x MFMA per barrier, staging traffic
//       512->402 MB/step. Grid 256 blocks (1/CU); panel-mates b, b+64 still
//       share an XCD (64%8==0).
// ---------------------------------------------------------------------------

typedef __attribute__((ext_vector_type(4))) float f32x4;
typedef __attribute__((ext_vector_type(8))) short short8;

__device__ __forceinline__ unsigned short f2b(float f) {
    union { float f; unsigned int u; } v;
    v.f = f;
    unsigned int r = v.u + 0x7fffu + ((v.u >> 16) & 1u);
    return (unsigned short)(r >> 16);
}

__device__ __forceinline__ float clamp01(float v) {
    return fminf(fmaxf(v, 0.0f), 1.0f);
}

__device__ __forceinline__ void async16(const unsigned short* g, unsigned short* l) {
    __builtin_amdgcn_global_load_lds(
        (__attribute__((address_space(1))) void*)g,
        (__attribute__((address_space(3))) void*)l,
        16, 0, 0);
}

// LDS tiles: rows of 8 chunks (16B each); chunk position within a row is
// XOR-swizzled by (row&7) so ds_read_b128 fragment reads spread banks.
__device__ __forceinline__ short8 frag_ld(const unsigned short* lds, int row, int ksel) {
    int chunk = (row << 3) + (ksel ^ (row & 7));
    return *reinterpret_cast<const short8*>(lds + (chunk << 3));
}

// A tile: 128 rows x 64 cols = 1024 16B chunks, 4 per thread.
__device__ __forceinline__ void stageA128(
    const unsigned short* __restrict__ Ag, int K, int M0, int k0,
    unsigned short* lds, int tid)
{
#pragma unroll
    for (int r = 0; r < 4; ++r) {
        int ca = (r << 8) + tid;
        int row = ca >> 3, kcs = ca & 7;
        int kc = kcs ^ (row & 7);
        async16(Ag + (size_t)(M0 + row) * K + k0 + (kc << 3), lds + (ca << 3));
    }
}

// B tile: 64 rows x 64 cols = 512 16B chunks, 2 per thread.
__device__ __forceinline__ void stageB64(
    const unsigned short* __restrict__ Bg, int K, int N0, int k0,
    unsigned short* lds, int tid)
{
#pragma unroll
    for (int r = 0; r < 2; ++r) {
        int cb = (r << 8) + tid;
        int row = cb >> 3, kcs = cb & 7;
        int kc = kcs ^ (row & 7);
        async16(Bg + (size_t)(N0 + row) * K + k0 + (kc << 3), lds + (cb << 3));
    }
}

// Core: C[128x64] tile of A[256,K] @ B^T[N,K] at (M0,N0). 256 threads, 4 waves
// in 2x2 layout, each wave owns a 64x32 sub-tile (4 M-frags x 2 N-frags).
// BK=64, double-buffered LDS, one barrier per K-step:
//   prologue: stage(buf0); sync
//   iter t:   stage(buf[cur^1], t+1); ds_read+MFMA on buf[cur]; sync; flip
// Reuse of buf[cur^1] is safe: its readers finished before the previous
// barrier (MFMA data-deps force lgkmcnt before the wave reaches it), and the
// stage is issued after that barrier. The sync's vmcnt(0) drain overlaps with
// this iteration's compute instead of being serially exposed.
// doS3 wave-uniform: wn==0 waves of the nt==0 GEMM1 blocks also accumulate
// acc2 = A_rows @ FW2T^T (16 cols) reusing A fragments.
__device__ __forceinline__ void gemm_core(
    const unsigned short* __restrict__ Ag,
    const unsigned short* __restrict__ Bg,
    int K, int M0, int N0,
    unsigned short (*ldsA)[128 * 64], unsigned short (*ldsB)[64 * 64],
    f32x4* acc,
    const unsigned short* __restrict__ FW2T, f32x4* acc2, bool doS3,
    int tid)
{
    const int lane = tid & 63;
    const int wave = tid >> 6;
    const int wm = (wave >> 1) << 6;   // 0 / 64
    const int wn = (wave & 1) << 5;    // 0 / 32
    const int fr = lane & 15;
    const int fq = lane >> 4;
    const int nks = K >> 6;

    stageA128(Ag, K, M0, 0, ldsA[0], tid);
    stageB64(Bg, K, N0, 0, ldsB[0], tid);
    __syncthreads();                   // drain prologue stage
    int cur = 0;

    for (int ks = 0; ks < nks; ++ks) {
        const int k0 = ks << 6;
        if (ks + 1 < nks) {            // issue NEXT tile before computing
            stageA128(Ag, K, M0, k0 + 64, ldsA[cur ^ 1], tid);
            stageB64(Bg, K, N0, k0 + 64, ldsB[cur ^ 1], tid);
        }
#pragma unroll
        for (int ki = 0; ki < 2; ++ki) {
            const int ksel = (ki << 2) + fq;
            short8 a0 = frag_ld(ldsA[cur], wm + fr, ksel);
            short8 a1 = frag_ld(ldsA[cur], wm + 16 + fr, ksel);
            short8 a2 = frag_ld(ldsA[cur], wm + 32 + fr, ksel);
            short8 a3 = frag_ld(ldsA[cur], wm + 48 + fr, ksel);
            short8 b0 = frag_ld(ldsB[cur], wn + fr, ksel);
            short8 b1 = frag_ld(ldsB[cur], wn + 16 + fr, ksel);
            acc[0] = __builtin_amdgcn_mfma_f32_16x16x32_bf16(a0, b0, acc[0], 0, 0, 0);
            acc[1] = __builtin_amdgcn_mfma_f32_16x16x32_bf16(a0, b1, acc[1], 0, 0, 0);
            acc[2] = __builtin_amdgcn_mfma_f32_16x16x32_bf16(a1, b0, acc[2], 0, 0, 0);
            acc[3] = __builtin_amdgcn_mfma_f32_16x16x32_bf16(a1, b1, acc[3], 0, 0, 0);
            acc[4] = __builtin_amdgcn_mfma_f32_16x16x32_bf16(a2, b0, acc[4], 0, 0, 0);
            acc[5] = __builtin_amdgcn_mfma_f32_16x16x32_bf16(a2, b1, acc[5], 0, 0, 0);
            acc[6] = __builtin_amdgcn_mfma_f32_16x16x32_bf16(a3, b0, acc[6], 0, 0, 0);
            acc[7] = __builtin_amdgcn_mfma_f32_16x16x32_bf16(a3, b1, acc[7], 0, 0, 0);
            if (doS3) {
                short8 bs = *reinterpret_cast<const short8*>(
                    FW2T + (size_t)fr * 4096 + k0 + (ksel << 3));
                acc2[0] = __builtin_amdgcn_mfma_f32_16x16x32_bf16(a0, bs, acc2[0], 0, 0, 0);
                acc2[1] = __builtin_amdgcn_mfma_f32_16x16x32_bf16(a1, bs, acc2[1], 0, 0, 0);
                acc2[2] = __builtin_amdgcn_mfma_f32_16x16x32_bf16(a2, bs, acc2[2], 0, 0, 0);
                acc2[3] = __builtin_amdgcn_mfma_f32_16x16x32_bf16(a3, bs, acc2[3], 0, 0, 0);
            }
        }
        __syncthreads();               // drains vmcnt -> next buffer valid
        cur ^= 1;
    }
}

// One relaxation step. Grid = 256 blocks: [0,128) GEMM1 (-> s1, s3),
// [128,256) GEMM2 (-> s2). 128x64 tiles over [256, 4096]. nt is the fast
// block index so panel-mates (b, b+64) land on the same XCD (64%8==0).
__global__ __launch_bounds__(256) void step_kernel(
    const unsigned short* __restrict__ R2old,
    const unsigned short* __restrict__ R1old,
    const float* __restrict__ S1old, const float* __restrict__ S2old,
    const float* __restrict__ S3old,
    float* __restrict__ S1new, float* __restrict__ S2new, float* __restrict__ S3new,
    unsigned short* __restrict__ R1new, unsigned short* __restrict__ R2new,
    const unsigned short* __restrict__ B1T, const unsigned short* __restrict__ B2T,
    const unsigned short* __restrict__ FW2T,
    const float* __restrict__ CC, const float* __restrict__ bw2,
    const float* __restrict__ y, float beta)
{
    __shared__ __align__(16) unsigned short ldsA[2][128 * 64];
    __shared__ __align__(16) unsigned short ldsB[2][64 * 64];
    const int tid = threadIdx.x;
    const int b = blockIdx.x;
    const bool g1 = (b < 128);
    int mt, nt;
    const unsigned short *A, *B;
    if (g1) { mt = b >> 6; nt = b & 63; A = R2old; B = B1T; }
    else    { int bb = b - 128; mt = bb >> 6; nt = bb & 63; A = R1old; B = B2T; }
    const int M0 = mt << 7, N0 = nt << 6;

    const int lane = tid & 63;
    const int wave = tid >> 6;
    const int wm = (wave >> 1) << 6;
    const int wn = (wave & 1) << 5;
    const int fr = lane & 15;
    const int fq = lane >> 4;
    // s3 head: wave-uniform predicate; wn==0 waves of nt==0 GEMM1 blocks
    const bool doS3 = g1 && (nt == 0) && (wn == 0);

    f32x4 acc[8], acc2[4];
    f32x4 zero = {0.f, 0.f, 0.f, 0.f};
#pragma unroll
    for (int i = 0; i < 8; ++i) acc[i] = zero;
#pragma unroll
    for (int i = 0; i < 4; ++i) acc2[i] = zero;

    gemm_core(A, B, 4096, M0, N0, ldsA, ldsB, acc, FW2T, acc2, doS3, tid);

    if (g1) {
#pragma unroll
        for (int f = 0; f < 4; ++f) {
#pragma unroll
            for (int in_ = 0; in_ < 2; ++in_) {
                int n = N0 + wn + (in_ << 4) + fr;
                f32x4 av = acc[(f << 1) + in_];
#pragma unroll
                for (int rr = 0; rr < 4; ++rr) {
                    int m = M0 + wm + (f << 4) + (fq << 2) + rr;
                    size_t o = (size_t)m * 4096 + n;
                    float v = 0.5f * S1old[o] + CC[o] + 0.25f * av[rr];
                    v = clamp01(v);
                    S1new[o] = v;
                    R1new[o] = f2b(v);
                }
            }
        }
        if (doS3 && fr < 10) {
#pragma unroll
            for (int f = 0; f < 4; ++f) {
#pragma unroll
                for (int rr = 0; rr < 4; ++rr) {
                    int m = M0 + wm + (f << 4) + (fq << 2) + rr;
                    float s3 = S3old[m * 10 + fr];
                    float v = (0.5f - beta) * s3 + 0.5f * acc2[f][rr]
                              + beta * y[m * 10 + fr];
                    v = clamp01(v);
                    S3new[m * 10 + fr] = v;
                }
            }
        }
    } else {
#pragma unroll
        for (int f = 0; f < 4; ++f) {
#pragma unroll
            for (int in_ = 0; in_ < 2; ++in_) {
                int n = N0 + wn + (in_ << 4) + fr;
                f32x4 av = acc[(f << 1) + in_];
#pragma unroll
                for (int rr = 0; rr < 4; ++rr) {
                    int m = M0 + wm + (f << 4) + (fq << 2) + rr;
                    size_t o = (size_t)m * 4096 + n;
                    float dot = 0.f;
#pragma unroll
                    for (int j = 0; j < 10; ++j)
                        dot += S3old[m * 10 + j] * bw2[j * 4096 + n];
                    float v = 0.5f * S2old[o] + 0.25f * av[rr] + 0.25f * dot;
                    v = clamp01(v);
                    S2new[o] = v;
                    R2new[o] = f2b(v);
                }
            }
        }
    }
}

// CC = 0.25*(rx @ fw0). A = RX [256,1024] bf16, B = FW0T [4096,1024] bf16.
// 128x64 tiles -> 128 blocks.
__global__ __launch_bounds__(256) void c1_kernel(
    const unsigned short* __restrict__ RX,
    const unsigned short* __restrict__ FW0T,
    float* __restrict__ CC)
{
    __shared__ __align__(16) unsigned short ldsA[2][128 * 64];
    __shared__ __align__(16) unsigned short ldsB[2][64 * 64];
    const int tid = threadIdx.x;
    const int b = blockIdx.x;
    const int mt = b >> 6, nt = b & 63;
    const int M0 = mt << 7, N0 = nt << 6;

    f32x4 acc[8], acc2[4];
    f32x4 zero = {0.f, 0.f, 0.f, 0.f};
#pragma unroll
    for (int i = 0; i < 8; ++i) acc[i] = zero;
#pragma unroll
    for (int i = 0; i < 4; ++i) acc2[i] = zero;

    gemm_core(RX, FW0T, 1024, M0, N0, ldsA, ldsB, acc, nullptr, acc2, false, tid);

    const int lane = tid & 63;
    const int wave = tid >> 6;
    const int wm = (wave >> 1) << 6;
    const int wn = (wave & 1) << 5;
    const int fr = lane & 15;
    const int fq = lane >> 4;
#pragma unroll
    for (int f = 0; f < 4; ++f) {
#pragma unroll
        for (int in_ = 0; in_ < 2; ++in_) {
            int n = N0 + wn + (in_ << 4) + fr;
            f32x4 av = acc[(f << 1) + in_];
#pragma unroll
            for (int rr = 0; rr < 4; ++rr) {
                int m = M0 + wm + (f << 4) + (fq << 2) + rr;
                CC[(size_t)m * 4096 + n] = 0.25f * av[rr];
            }
        }
    }
}

// src [R][C] fp32 row-major -> dst [C][R] bf16 (dst row stride = R).
__global__ __launch_bounds__(256) void transpose_cvt(
    const float* __restrict__ src, unsigned short* __restrict__ dst,
    int R, int C)
{
    __shared__ float t[32][33];
    const int c0 = blockIdx.x << 5, r0 = blockIdx.y << 5;
    const int tx = threadIdx.x & 31, ty = threadIdx.x >> 5;   // ty: 0..7
#pragma unroll
    for (int i = 0; i < 32; i += 8)
        t[ty + i][tx] = src[(size_t)(r0 + ty + i) * C + (c0 + tx)];
    __syncthreads();
#pragma unroll
    for (int i = 0; i < 32; i += 8)
        dst[(size_t)(c0 + ty + i) * R + (r0 + tx)] = f2b(t[tx][ty + i]);
}

// FW2T fill, rx convert, zero-init of ping buffers.
__global__ __launch_bounds__(256) void misc_init(
    const float* __restrict__ x, const float* __restrict__ fw2,
    unsigned short* __restrict__ FW2T, unsigned short* __restrict__ RX,
    float* __restrict__ S1, float* __restrict__ S2, float* __restrict__ S3,
    unsigned short* __restrict__ R1, unsigned short* __restrict__ R2)
{
    const int stride = gridDim.x * blockDim.x;
    const int t0 = blockIdx.x * blockDim.x + threadIdx.x;
    for (int i = t0; i < 16 * 4096; i += stride) {      // FW2T[n][k] = fw2[k][n]
        int n = i >> 12, k = i & 4095;
        FW2T[i] = (n < 10) ? f2b(fw2[k * 10 + n]) : (unsigned short)0;
    }
    for (int i = t0; i < 256 * 1024; i += stride)
        RX[i] = f2b(clamp01(x[i]));
    for (int i = t0; i < 256 * 4096; i += stride) {
        S1[i] = 0.f; S2[i] = 0.f; R1[i] = 0; R2[i] = 0;
    }
    for (int i = t0; i < 2560; i += stride) S3[i] = 0.f;
}

__global__ __launch_bounds__(256) void pack_kernel(
    const float* __restrict__ S1, const float* __restrict__ S2,
    const float* __restrict__ S3, float* __restrict__ out)
{
    const int stride = gridDim.x * blockDim.x;
    for (int i = blockIdx.x * blockDim.x + threadIdx.x; i < 256 * 8202; i += stride) {
        int m = i / 8202, c = i - m * 8202;
        float v;
        if (c < 4096)       v = S1[(size_t)m * 4096 + c];
        else if (c < 8192)  v = S2[(size_t)m * 4096 + (c - 4096)];
        else                v = S3[m * 10 + (c - 8192)];
        out[i] = v;
    }
}

extern "C" void kernel_launch(void* const* d_in, const int* in_sizes, int n_in,
                              void* d_out, int out_size, void* d_ws, size_t ws_size,
                              hipStream_t stream) {
    const float* x   = (const float*)d_in[0];
    const float* fw0 = (const float*)d_in[1];
    const float* fw1 = (const float*)d_in[2];
    const float* fw2 = (const float*)d_in[3];
    // d_in[4] = bw0 : unused by the reference
    const float* bw1 = (const float*)d_in[5];
    const float* bw2 = (const float*)d_in[6];
    const float* y   = (const float*)d_in[7];

    char* ws = (char*)d_ws;
    // workspace layout (bytes)
    unsigned short* B1T  = (unsigned short*)(ws + 0);          // 4096x4096 bf16
    unsigned short* B2T  = (unsigned short*)(ws + 33554432);   // 4096x4096 bf16
    unsigned short* FW0T = (unsigned short*)(ws + 67108864);   // 4096x1024 bf16
    unsigned short* FW2T = (unsigned short*)(ws + 75497472);   // 16x4096 bf16
    unsigned short* RX   = (unsigned short*)(ws + 75628544);   // 256x1024 bf16
    float*          CC   = (float*)(ws + 76152832);            // 256x4096 f32
    float*          S1f  = (float*)(ws + 80347136);            // 2 x 256x4096 f32
    float*          S2f  = (float*)(ws + 88735744);            // 2 x 256x4096 f32
    float*          S3f  = (float*)(ws + 97124352);            // 2 x 256x10 f32
    unsigned short* R1   = (unsigned short*)(ws + 97144832);   // 2 x 256x4096 bf16
    unsigned short* R2   = (unsigned short*)(ws + 101339136);  // 2 x 256x4096 bf16
    // total ~105.6 MB

    const size_t SB = 256 * 4096;  // state buffer elems
    dim3 blk(256);

    transpose_cvt<<<dim3(128, 128), blk, 0, stream>>>(bw1, B1T, 4096, 4096);
    transpose_cvt<<<dim3(128, 128), blk, 0, stream>>>(fw1, B2T, 4096, 4096);
    transpose_cvt<<<dim3(128, 32),  blk, 0, stream>>>(fw0, FW0T, 1024, 4096);
    misc_init<<<512, blk, 0, stream>>>(x, fw2, FW2T, RX,
                                       S1f, S2f, S3f, R1, R2);
    c1_kernel<<<128, blk, 0, stream>>>(RX, FW0T, CC);

    for (int t = 0; t < 25; ++t) {
        const int o = t & 1, nw = o ^ 1;
        const float beta = (t < 20) ? 0.0f : 0.5f;
        step_kernel<<<256, blk, 0, stream>>>(
            R2 + o * SB, R1 + o * SB,
            S1f + o * SB, S2f + o * SB, S3f + o * 2560,
            S1f + nw * SB, S2f + nw * SB, S3f + nw * 2560,
            R1 + nw * SB, R2 + nw * SB,
            B1T, B2T, FW2T, CC, bw2, y, beta);
    }

    pack_kernel<<<2048, blk, 0, stream>>>(S1f + SB, S2f + SB, S3f + 2560,
                                          (float*)d_out);
}

// Round 2
// 1144.862 us; speedup vs baseline: 2.1751x; 2.1751x over previous
//
#include <hip/hip_runtime.h>

// ---------------------------------------------------------------------------
// BidirectionalMLP equilibrium relaxation on MI355X.
// s1,s2: [256,4096], s3: [256,10].  25 steps of:
//   s1' = clip(0.5*s1 + CC + 0.25*(r2@bw1))          CC = 0.25*(rx@fw0), const
//   s2' = clip(0.5*s2 + 0.25*(r1@fw1) + 0.25*(r3@bw2))
//   s3' = clip((0.5-beta)*s3 + 0.5*(r2@fw2) + beta*y)
// bf16 MFMA 16x16x32, fp32 accum. Weights transposed once to [N][K] bf16.
// Round 5: counted-vmcnt software pipeline (T3+T4). Round-4's dbuf failed:
// __syncthreads drains vmcnt(0) every K-step and grid 256 = 1 block/CU lost
// the cross-block interleave (Occupancy 12.6->7.5, dur 82->95us).
// Now: 64x64 tiles, grid 512 (2 blocks/CU), 4-slot LDS ring, prefetch depth
// 3, ONE raw s_barrier + ONE counted "s_waitcnt vmcnt(8)" per K-step (peeled
// tail: vmcnt(4)/vmcnt(0)). Loads for tile ks are issued 3 iterations early
// (~450-600cy of MFMA+ds_read cover >= L2 latency). s3 head reads FW2T from
// a small staged LDS ring (a register-result global load inside the MFMA
// phase would make the compiler wait on the YOUNGEST vmem op = full drain).
// ---------------------------------------------------------------------------

typedef __attribute__((ext_vector_type(4))) float f32x4;
typedef __attribute__((ext_vector_type(8))) short short8;

__device__ __forceinline__ unsigned short f2b(float f) {
    union { float f; unsigned int u; } v;
    v.f = f;
    unsigned int r = v.u + 0x7fffu + ((v.u >> 16) & 1u);
    return (unsigned short)(r >> 16);
}

__device__ __forceinline__ float clamp01(float v) {
    return fminf(fmaxf(v, 0.0f), 1.0f);
}

__device__ __forceinline__ void async16(const unsigned short* g, unsigned short* l) {
    __builtin_amdgcn_global_load_lds(
        (__attribute__((address_space(1))) void*)g,
        (__attribute__((address_space(3))) void*)l,
        16, 0, 0);
}

// LDS tiles: rows of 8 chunks (16B each); chunk position within a row is
// XOR-swizzled by (row&7) applied to the GLOBAL source k-chunk so the LDS
// destination stays linear (global_load_lds requirement) while ds_read_b128
// fragment reads spread banks.
__device__ __forceinline__ short8 frag_ld(const unsigned short* lds, int row, int ksel) {
    int chunk = (row << 3) + (ksel ^ (row & 7));
    return *reinterpret_cast<const short8*>(lds + (chunk << 3));
}

#define MFMA_BF16 __builtin_amdgcn_mfma_f32_16x16x32_bf16

// Core: C[64x64] tile of A[256,K] @ B^T[N,K] at (M0,N0). 256 threads, 4 waves
// in 2x2 layout (each wave 32x32). BK=64, 4-slot ring, prefetch depth 3.
// Steady-state K-step:
//   vmcnt(8)    -- own 4 loads of tile ks complete (2 newer stages in flight)
//   s_barrier   -- all waves' tile-ks loads complete -> slot valid
//   ds_read frags of slot ks&3
//   stage tile ks+3 into slot (ks+3)&3   (never the slot being read; the
//     barrier retired all waves' reads of that slot last iteration)
//   MFMA x16 (+4 for s3 head)
// vmcnt NEVER drains to 0 in the main loop; tail peeled with vmcnt(4)/(0).
// s3blk: block-uniform flag; waves 0,1 additionally stage FW2T[16x64] per
// slot (their vmcnt gates stay conservative: 5 loads/stage vs 4).
__device__ __forceinline__ void gemm_core(
    const unsigned short* __restrict__ Ag,
    const unsigned short* __restrict__ Bg,
    int K, int M0, int N0,
    unsigned short (*ldsA)[64 * 64], unsigned short (*ldsB)[64 * 64],
    unsigned short (*ldsS)[16 * 64],
    f32x4* acc,
    const unsigned short* __restrict__ FW2T, f32x4* acc2,
    bool s3blk, bool doS3,
    int tid)
{
    const int lane = tid & 63;
    const int wave = tid >> 6;
    const int wm = (wave >> 1) << 5;   // 0 / 32
    const int wn = (wave & 1) << 5;    // 0 / 32
    const int fr = lane & 15;
    const int fq = lane >> 4;
    const int nks = K >> 6;

    auto STAGE = [&](int ks) {
        const int slot = ks & 3;
        const int k0 = ks << 6;
        unsigned short* lA = ldsA[slot];
        unsigned short* lB = ldsB[slot];
#pragma unroll
        for (int r = 0; r < 2; ++r) {  // A: 64 rows x 8 chunks = 512
            int ca = (r << 8) + tid;
            int row = ca >> 3, kcs = ca & 7;
            int kc = kcs ^ (row & 7);
            async16(Ag + (size_t)(M0 + row) * K + k0 + (kc << 3), lA + (ca << 3));
        }
#pragma unroll
        for (int r = 0; r < 2; ++r) {  // B: 64 rows x 8 chunks = 512
            int cb = (r << 8) + tid;
            int row = cb >> 3, kcs = cb & 7;
            int kc = kcs ^ (row & 7);
            async16(Bg + (size_t)(N0 + row) * K + k0 + (kc << 3), lB + (cb << 3));
        }
        if (s3blk && tid < 128) {      // FW2T: 16 rows x 8 chunks = 128
            int row = tid >> 3, kcs = tid & 7;
            int kc = kcs ^ (row & 7);
            async16(FW2T + (size_t)row * 4096 + k0 + (kc << 3),
                    ldsS[slot] + (tid << 3));
        }
    };

    auto BODY = [&](int ks, bool doStage) {
        const int slot = ks & 3;
        const unsigned short* lA = ldsA[slot];
        const unsigned short* lB = ldsB[slot];
        short8 A0[2], A1[2], B0[2], B1[2], BS[2];
#pragma unroll
        for (int ki = 0; ki < 2; ++ki) {
            const int ksel = (ki << 2) + fq;
            A0[ki] = frag_ld(lA, wm + fr, ksel);
            A1[ki] = frag_ld(lA, wm + 16 + fr, ksel);
            B0[ki] = frag_ld(lB, wn + fr, ksel);
            B1[ki] = frag_ld(lB, wn + 16 + fr, ksel);
            if (doS3) BS[ki] = frag_ld(ldsS[slot], fr, ksel);
        }
        if (doStage && ks + 3 < nks) STAGE(ks + 3);
#pragma unroll
        for (int ki = 0; ki < 2; ++ki) {
            acc[0] = MFMA_BF16(A0[ki], B0[ki], acc[0], 0, 0, 0);
            acc[1] = MFMA_BF16(A0[ki], B1[ki], acc[1], 0, 0, 0);
            acc[2] = MFMA_BF16(A1[ki], B0[ki], acc[2], 0, 0, 0);
            acc[3] = MFMA_BF16(A1[ki], B1[ki], acc[3], 0, 0, 0);
            if (doS3) {
                acc2[0] = MFMA_BF16(A0[ki], BS[ki], acc2[0], 0, 0, 0);
                acc2[1] = MFMA_BF16(A1[ki], BS[ki], acc2[1], 0, 0, 0);
            }
        }
    };

    STAGE(0); STAGE(1); STAGE(2);      // 3 tiles in flight

    int ks = 0;
    for (; ks < nks - 2; ++ks) {
        asm volatile("s_waitcnt vmcnt(8)" ::: "memory");
        __builtin_amdgcn_s_barrier();
        asm volatile("" ::: "memory");
        BODY(ks, true);
    }
    asm volatile("s_waitcnt vmcnt(4)" ::: "memory");
    __builtin_amdgcn_s_barrier();
    asm volatile("" ::: "memory");
    BODY(nks - 2, false);
    asm volatile("s_waitcnt vmcnt(0)" ::: "memory");
    __builtin_amdgcn_s_barrier();
    asm volatile("" ::: "memory");
    BODY(nks - 1, false);
}

// One relaxation step. Grid = 512 blocks: [0,256) GEMM1 (-> s1, s3),
// [256,512) GEMM2 (-> s2). 64x64 tiles over [256, 4096]. nt is the fast
// block index so panel-mates (b, b+64, ...) land on the same XCD (64%8==0).
__global__ __launch_bounds__(256) void step_kernel(
    const unsigned short* __restrict__ R2old,
    const unsigned short* __restrict__ R1old,
    const float* __restrict__ S1old, const float* __restrict__ S2old,
    const float* __restrict__ S3old,
    float* __restrict__ S1new, float* __restrict__ S2new, float* __restrict__ S3new,
    unsigned short* __restrict__ R1new, unsigned short* __restrict__ R2new,
    const unsigned short* __restrict__ B1T, const unsigned short* __restrict__ B2T,
    const unsigned short* __restrict__ FW2T,
    const float* __restrict__ CC, const float* __restrict__ bw2,
    const float* __restrict__ y, float beta)
{
    __shared__ __align__(16) unsigned short ldsA[4][64 * 64];
    __shared__ __align__(16) unsigned short ldsB[4][64 * 64];
    __shared__ __align__(16) unsigned short ldsS[4][16 * 64];
    const int tid = threadIdx.x;
    const int b = blockIdx.x;
    const bool g1 = (b < 256);
    int mt, nt;
    const unsigned short *A, *B;
    if (g1) { mt = b >> 6; nt = b & 63; A = R2old; B = B1T; }
    else    { int bb = b - 256; mt = bb >> 6; nt = bb & 63; A = R1old; B = B2T; }
    const int M0 = mt << 6, N0 = nt << 6;

    const int lane = tid & 63;
    const int wave = tid >> 6;
    const int wm = (wave >> 1) << 5;
    const int wn = (wave & 1) << 5;
    const int fr = lane & 15;
    const int fq = lane >> 4;
    const bool s3blk = g1 && (nt == 0);          // block-uniform
    const bool doS3 = s3blk && (wn == 0);        // wave-uniform

    f32x4 acc[4], acc2[2];
    f32x4 zero = {0.f, 0.f, 0.f, 0.f};
#pragma unroll
    for (int i = 0; i < 4; ++i) acc[i] = zero;
    acc2[0] = zero; acc2[1] = zero;

    gemm_core(A, B, 4096, M0, N0, ldsA, ldsB, ldsS, acc,
              FW2T, acc2, s3blk, doS3, tid);

    if (g1) {
#pragma unroll
        for (int i = 0; i < 4; ++i) {
            int im = i >> 1, in_ = i & 1;
            int n = N0 + wn + (in_ << 4) + fr;
#pragma unroll
            for (int rr = 0; rr < 4; ++rr) {
                int m = M0 + wm + (im << 4) + (fq << 2) + rr;
                size_t o = (size_t)m * 4096 + n;
                float v = 0.5f * S1old[o] + CC[o] + 0.25f * acc[i][rr];
                v = clamp01(v);
                S1new[o] = v;
                R1new[o] = f2b(v);
            }
        }
        if (doS3 && fr < 10) {
#pragma unroll
            for (int im = 0; im < 2; ++im) {
#pragma unroll
                for (int rr = 0; rr < 4; ++rr) {
                    int m = M0 + wm + (im << 4) + (fq << 2) + rr;
                    float s3 = S3old[m * 10 + fr];
                    float v = (0.5f - beta) * s3 + 0.5f * acc2[im][rr]
                              + beta * y[m * 10 + fr];
                    v = clamp01(v);
                    S3new[m * 10 + fr] = v;
                }
            }
        }
    } else {
#pragma unroll
        for (int i = 0; i < 4; ++i) {
            int im = i >> 1, in_ = i & 1;
            int n = N0 + wn + (in_ << 4) + fr;
#pragma unroll
            for (int rr = 0; rr < 4; ++rr) {
                int m = M0 + wm + (im << 4) + (fq << 2) + rr;
                size_t o = (size_t)m * 4096 + n;
                float dot = 0.f;
#pragma unroll
                for (int j = 0; j < 10; ++j)
                    dot += S3old[m * 10 + j] * bw2[j * 4096 + n];
                float v = 0.5f * S2old[o] + 0.25f * acc[i][rr] + 0.25f * dot;
                v = clamp01(v);
                S2new[o] = v;
                R2new[o] = f2b(v);
            }
        }
    }
}

// CC = 0.25*(rx @ fw0). A = RX [256,1024] bf16, B = FW0T [4096,1024] bf16.
// 64x64 tiles -> 256 blocks.
__global__ __launch_bounds__(256) void c1_kernel(
    const unsigned short* __restrict__ RX,
    const unsigned short* __restrict__ FW0T,
    float* __restrict__ CC)
{
    __shared__ __align__(16) unsigned short ldsA[4][64 * 64];
    __shared__ __align__(16) unsigned short ldsB[4][64 * 64];
    __shared__ __align__(16) unsigned short ldsS[4][16 * 64];
    const int tid = threadIdx.x;
    const int b = blockIdx.x;
    const int mt = b >> 6, nt = b & 63;
    const int M0 = mt << 6, N0 = nt << 6;

    f32x4 acc[4], acc2[2];
    f32x4 zero = {0.f, 0.f, 0.f, 0.f};
#pragma unroll
    for (int i = 0; i < 4; ++i) acc[i] = zero;
    acc2[0] = zero; acc2[1] = zero;

    gemm_core(RX, FW0T, 1024, M0, N0, ldsA, ldsB, ldsS, acc,
              nullptr, acc2, false, false, tid);

    const int lane = tid & 63;
    const int wave = tid >> 6;
    const int wm = (wave >> 1) << 5;
    const int wn = (wave & 1) << 5;
    const int fr = lane & 15;
    const int fq = lane >> 4;
#pragma unroll
    for (int i = 0; i < 4; ++i) {
        int im = i >> 1, in_ = i & 1;
        int n = N0 + wn + (in_ << 4) + fr;
#pragma unroll
        for (int rr = 0; rr < 4; ++rr) {
            int m = M0 + wm + (im << 4) + (fq << 2) + rr;
            CC[(size_t)m * 4096 + n] = 0.25f * acc[i][rr];
        }
    }
}

// src [R][C] fp32 row-major -> dst [C][R] bf16 (dst row stride = R).
__global__ __launch_bounds__(256) void transpose_cvt(
    const float* __restrict__ src, unsigned short* __restrict__ dst,
    int R, int C)
{
    __shared__ float t[32][33];
    const int c0 = blockIdx.x << 5, r0 = blockIdx.y << 5;
    const int tx = threadIdx.x & 31, ty = threadIdx.x >> 5;   // ty: 0..7
#pragma unroll
    for (int i = 0; i < 32; i += 8)
        t[ty + i][tx] = src[(size_t)(r0 + ty + i) * C + (c0 + tx)];
    __syncthreads();
#pragma unroll
    for (int i = 0; i < 32; i += 8)
        dst[(size_t)(c0 + ty + i) * R + (r0 + tx)] = f2b(t[tx][ty + i]);
}

// FW2T fill, rx convert, zero-init of ping buffers.
__global__ __launch_bounds__(256) void misc_init(
    const float* __restrict__ x, const float* __restrict__ fw2,
    unsigned short* __restrict__ FW2T, unsigned short* __restrict__ RX,
    float* __restrict__ S1, float* __restrict__ S2, float* __restrict__ S3,
    unsigned short* __restrict__ R1, unsigned short* __restrict__ R2)
{
    const int stride = gridDim.x * blockDim.x;
    const int t0 = blockIdx.x * blockDim.x + threadIdx.x;
    for (int i = t0; i < 16 * 4096; i += stride) {      // FW2T[n][k] = fw2[k][n]
        int n = i >> 12, k = i & 4095;
        FW2T[i] = (n < 10) ? f2b(fw2[k * 10 + n]) : (unsigned short)0;
    }
    for (int i = t0; i < 256 * 1024; i += stride)
        RX[i] = f2b(clamp01(x[i]));
    for (int i = t0; i < 256 * 4096; i += stride) {
        S1[i] = 0.f; S2[i] = 0.f; R1[i] = 0; R2[i] = 0;
    }
    for (int i = t0; i < 2560; i += stride) S3[i] = 0.f;
}

__global__ __launch_bounds__(256) void pack_kernel(
    const float* __restrict__ S1, const float* __restrict__ S2,
    const float* __restrict__ S3, float* __restrict__ out)
{
    const int stride = gridDim.x * blockDim.x;
    for (int i = blockIdx.x * blockDim.x + threadIdx.x; i < 256 * 8202; i += stride) {
        int m = i / 8202, c = i - m * 8202;
        float v;
        if (c < 4096)       v = S1[(size_t)m * 4096 + c];
        else if (c < 8192)  v = S2[(size_t)m * 4096 + (c - 4096)];
        else                v = S3[m * 10 + (c - 8192)];
        out[i] = v;
    }
}

extern "C" void kernel_launch(void* const* d_in, const int* in_sizes, int n_in,
                              void* d_out, int out_size, void* d_ws, size_t ws_size,
                              hipStream_t stream) {
    const float* x   = (const float*)d_in[0];
    const float* fw0 = (const float*)d_in[1];
    const float* fw1 = (const float*)d_in[2];
    const float* fw2 = (const float*)d_in[3];
    // d_in[4] = bw0 : unused by the reference
    const float* bw1 = (const float*)d_in[5];
    const float* bw2 = (const float*)d_in[6];
    const float* y   = (const float*)d_in[7];

    char* ws = (char*)d_ws;
    // workspace layout (bytes)
    unsigned short* B1T  = (unsigned short*)(ws + 0);          // 4096x4096 bf16
    unsigned short* B2T  = (unsigned short*)(ws + 33554432);   // 4096x4096 bf16
    unsigned short* FW0T = (unsigned short*)(ws + 67108864);   // 4096x1024 bf16
    unsigned short* FW2T = (unsigned short*)(ws + 75497472);   // 16x4096 bf16
    unsigned short* RX   = (unsigned short*)(ws + 75628544);   // 256x1024 bf16
    float*          CC   = (float*)(ws + 76152832);            // 256x4096 f32
    float*          S1f  = (float*)(ws + 80347136);            // 2 x 256x4096 f32
    float*          S2f  = (float*)(ws + 88735744);            // 2 x 256x4096 f32
    float*          S3f  = (float*)(ws + 97124352);            // 2 x 256x10 f32
    unsigned short* R1   = (unsigned short*)(ws + 97144832);   // 2 x 256x4096 bf16
    unsigned short* R2   = (unsigned short*)(ws + 101339136);  // 2 x 256x4096 bf16
    // total ~105.6 MB

    const size_t SB = 256 * 4096;  // state buffer elems
    dim3 blk(256);

    transpose_cvt<<<dim3(128, 128), blk, 0, stream>>>(bw1, B1T, 4096, 4096);
    transpose_cvt<<<dim3(128, 128), blk, 0, stream>>>(fw1, B2T, 4096, 4096);
    transpose_cvt<<<dim3(128, 32),  blk, 0, stream>>>(fw0, FW0T, 1024, 4096);
    misc_init<<<512, blk, 0, stream>>>(x, fw2, FW2T, RX,
                                       S1f, S2f, S3f, R1, R2);
    c1_kernel<<<256, blk, 0, stream>>>(RX, FW0T, CC);

    for (int t = 0; t < 25; ++t) {
        const int o = t & 1, nw = o ^ 1;
        const float beta = (t < 20) ? 0.0f : 0.5f;
        step_kernel<<<512, blk, 0, stream>>>(
            R2 + o * SB, R1 + o * SB,
            S1f + o * SB, S2f + o * SB, S3f + o * 2560,
            S1f + nw * SB, S2f + nw * SB, S3f + nw * 2560,
            R1 + nw * SB, R2 + nw * SB,
            B1T, B2T, FW2T, CC, bw2, y, beta);
    }

    pack_kernel<<<2048, blk, 0, stream>>>(S1f + SB, S2f + SB, S3f + 2560,
                                          (float*)d_out);
}